// Round 1
// baseline (94.251 us; speedup 1.0000x reference)
//
#include <hip/hip_runtime.h>
#include <cstdint>
#include <cstddef>

#define RANK 16

// ---------------------------------------------------------------------------
// Kernel 1: mix LoRA factors with per-(batch,split) skill weights.
//   Am[b][k][r] = sum_s w[b][q][s] * la[q][s][d][r],      k = q*512 + d
//   Bm[b][r][o] = 2 * sum_s w[b][q][s] * lb[q][s][r][dd], o = q*512 + dd
// (scaling = lora_alpha/rank = 2, folded into Bm)
// ---------------------------------------------------------------------------
__global__ __launch_bounds__(256) void skilled_lora_mix(
    const float* __restrict__ w,   // [8][4][8]
    const float* __restrict__ la,  // [4][8][512][16]
    const float* __restrict__ lb,  // [4][8][16][512]
    float* __restrict__ Am,        // [8][2048][16]
    float* __restrict__ Bm)        // [8][16][2048], pre-scaled by 2
{
  const int j = blockIdx.x * 256 + threadIdx.x;   // one float4 per thread
  if (j < 65536) {
    const int r0 = (j & 3) * 4;
    const int k  = (j >> 2) & 2047;
    const int b  = j >> 13;
    const int q  = k >> 9;
    const int d  = k & 511;
    const float* wb = w + (b * 4 + q) * 8;
    float4 acc = make_float4(0.f, 0.f, 0.f, 0.f);
#pragma unroll
    for (int s = 0; s < 8; ++s) {
      const float ws = wb[s];
      const float4 v = *reinterpret_cast<const float4*>(
          la + (size_t)(((q * 8 + s) * 512 + d) * 16 + r0));
      acc.x = fmaf(ws, v.x, acc.x);
      acc.y = fmaf(ws, v.y, acc.y);
      acc.z = fmaf(ws, v.z, acc.z);
      acc.w = fmaf(ws, v.w, acc.w);
    }
    *reinterpret_cast<float4*>(Am + (size_t)((b * 2048 + k) * 16 + r0)) = acc;
  } else {
    const int jj = j - 65536;
    const int o  = (jj & 511) * 4;
    const int r  = (jj >> 9) & 15;
    const int b  = jj >> 13;
    const int q  = o >> 9;
    const int dd = o & 511;
    const float* wb = w + (b * 4 + q) * 8;
    float4 acc = make_float4(0.f, 0.f, 0.f, 0.f);
#pragma unroll
    for (int s = 0; s < 8; ++s) {
      const float ws = wb[s];
      const float4 v = *reinterpret_cast<const float4*>(
          lb + (size_t)(((q * 8 + s) * 16 + r) * 512 + dd));
      acc.x = fmaf(ws, v.x, acc.x);
      acc.y = fmaf(ws, v.y, acc.y);
      acc.z = fmaf(ws, v.z, acc.z);
      acc.w = fmaf(ws, v.w, acc.w);
    }
    acc.x *= 2.f; acc.y *= 2.f; acc.z *= 2.f; acc.w *= 2.f;
    *reinterpret_cast<float4*>(Bm + (size_t)((b * 16 + r) * 2048 + o)) = acc;
  }
}

// ---------------------------------------------------------------------------
// Kernel 2: fused  tmp = input @ Am ;  out = tmp @ Bm
// One block per (batch b, 64-row tile). 512 threads = 8 waves, 1 block/CU.
// Phase 1: lane = row; wave w owns K-range [w*256, w*256+256).
//          A operand is wave-uniform -> SGPR loads (zero vector-mem cost).
// Phase 2: lane = out column (coalesced float4 stores); tmp via LDS broadcast.
// ---------------------------------------------------------------------------
#define WAVES   8
#define ROWS    64
#define KRANGE  256
#define KCHUNK  64
#define STRIDE  65                     // 65-float row stride: 2-way bank alias (free)
#define BUFSZ   (ROWS * STRIDE)        // 4160 floats per wave

__global__ __launch_bounds__(512, 2) void skilled_lora_fused(
    const float* __restrict__ input,   // [8][2048][2048]
    const float* __restrict__ Am,      // [8][2048][16]
    const float* __restrict__ Bm,      // [8][16][2048]
    float* __restrict__ out)           // [8][2048][2048]
{
  __shared__ float lds[WAVES * BUFSZ + ROWS * RANK];  // 34304 floats = 137.2 KB

  const int tid  = threadIdx.x;
  const int lane = tid & 63;
  const int wv   = __builtin_amdgcn_readfirstlane(tid >> 6);  // provably wave-uniform
  const int b    = blockIdx.x >> 5;           // 0..7
  const int s0   = (blockIdx.x & 31) * ROWS;  // row-tile base

  float* buf = lds + wv * BUFSZ;
  float* tmp = lds + WAVES * BUFSZ;           // [64][16]

  // ---------------- phase 1: partial tmp = input-rows @ A (this wave's K) ---
  const float* Ab  = Am + (size_t)b * (2048 * RANK) + (size_t)wv * (KRANGE * RANK);
  const float* inb = input + ((size_t)(b * 2048 + s0)) * 2048 + wv * KRANGE;

  float acc[RANK];
#pragma unroll
  for (int r = 0; r < RANK; ++r) acc[r] = 0.f;

  for (int c = 0; c < KRANGE / KCHUNK; ++c) {
    const float* src0 = inb + c * KCHUNK;
    // stage 64 rows x 64 floats into this wave's private LDS buffer
#pragma unroll 8
    for (int row = 0; row < ROWS; ++row) {
      buf[row * STRIDE + lane] = src0[(size_t)row * 2048 + lane];
    }
    __builtin_amdgcn_s_waitcnt(0);  // drain vm+lgkm before reading (wave-private buf)
    const float* Ac = Ab + c * (KCHUNK * RANK);
#pragma unroll 4
    for (int kk = 0; kk < KCHUNK; ++kk) {
      const float x = buf[lane * STRIDE + kk];
#pragma unroll
      for (int r = 0; r < RANK; ++r)
        acc[r] = fmaf(x, Ac[kk * RANK + r], acc[r]);  // Ac[..] wave-uniform -> s_load
    }
  }

  // park partials in this wave's staging buffer, then cross-wave reduce
#pragma unroll
  for (int r = 0; r < RANK; ++r) buf[lane * STRIDE + r] = acc[r];
  __syncthreads();

  for (int v = tid; v < ROWS * RANK; v += 512) {
    const int row = v >> 4;
    const int r   = v & 15;
    float s = 0.f;
#pragma unroll
    for (int wvv = 0; wvv < WAVES; ++wvv)
      s += lds[wvv * BUFSZ + row * STRIDE + r];
    tmp[v] = s;   // tmp[row*16 + r]
  }
  __syncthreads();

  // ---------------- phase 2: out = tmp @ B (B pre-scaled by 2) --------------
  const int rowg = (wv & 1) * 32;       // row half
  const int oq   = (wv >> 1) * 512;     // o quarter
  const float* Bb = Bm + (size_t)b * (RANK * 2048);
  float* outb = out + ((size_t)(b * 2048 + s0 + rowg)) * 2048;

  for (int it = 0; it < 2; ++it) {
    const int o0 = oq + it * 256 + lane * 4;
    float4 B4[RANK];
#pragma unroll
    for (int r = 0; r < RANK; ++r)
      B4[r] = *reinterpret_cast<const float4*>(Bb + (size_t)r * 2048 + o0);
#pragma unroll 2
    for (int row = 0; row < 32; ++row) {
      const float* tr = tmp + (rowg + row) * RANK;   // uniform addr -> LDS broadcast
      float4 a = make_float4(0.f, 0.f, 0.f, 0.f);
#pragma unroll
      for (int r = 0; r < RANK; ++r) {
        const float tv = tr[r];
        a.x = fmaf(tv, B4[r].x, a.x);
        a.y = fmaf(tv, B4[r].y, a.y);
        a.z = fmaf(tv, B4[r].z, a.z);
        a.w = fmaf(tv, B4[r].w, a.w);
      }
      *reinterpret_cast<float4*>(outb + (size_t)row * 2048 + o0) = a;
    }
  }
}

// ---------------------------------------------------------------------------
extern "C" void kernel_launch(void* const* d_in, const int* in_sizes, int n_in,
                              void* d_out, int out_size, void* d_ws, size_t ws_size,
                              hipStream_t stream) {
  const float* input = (const float*)d_in[0];   // [8][2048][2048]
  const float* w     = (const float*)d_in[1];   // [8][4][8]
  const float* la    = (const float*)d_in[2];   // [4][8][512][16]
  const float* lb    = (const float*)d_in[3];   // [4][8][16][512]
  float* outp = (float*)d_out;

  float* Am = (float*)d_ws;                     // 262144 floats (1 MB)
  float* Bm = Am + 8 * 2048 * RANK;             // 262144 floats (1 MB)

  skilled_lora_mix<<<512, 256, 0, stream>>>(w, la, lb, Am, Bm);
  skilled_lora_fused<<<256, 512, 0, stream>>>(input, Am, Bm, outp);
}